// Round 6
// baseline (163.574 us; speedup 1.0000x reference)
//
#include <hip/hip_runtime.h>

// GraphAutoEncoder: FOUR threads per graph (B=131072, N=8), one role per wave
// (wave w handles role w; lane L of all 4 waves = graph g of the block).
// Role split: encoder 2 nodes, Gabriel 7 pairs, GCN1 8 features, folded
// decoder 16 h's. n/cj duplicated per role (kills one barrier + 16 ds_reads).
// 4 barriers, 10 KB LDS, __launch_bounds__(256,8) -> 8 blocks/CU.
// Global stores deferred to kernel end (no vmcnt drain at barriers).
// All decision + accumulation arithmetic bit-identical to rounds 2-5.

typedef float v2 __attribute__((ext_vector_type(2)));
static __device__ __forceinline__ v2 sp(float s) { return (v2){s, s}; }
static __device__ __forceinline__ v2 fma2(v2 a, v2 b, v2 c) {
    return __builtin_elementwise_fma(a, b, c);
}
static __device__ __forceinline__ v2 ldv2(const float* p) {
    return *reinterpret_cast<const v2*>(p);
}

// ws layout (floats):
//   [0,2048)    Wdec[32][64] = gcn2_w @ dec_w1
//   [2048,2112) cdec[64]     = gcn2_b @ dec_w1 + dec_b1
//   [2112,2176) w2col[64]    = dec_w2[:,1]
//   [2176,2688) ctab[64][8]  : ctab[h*8+i] = fmaf(i, enc_w1[128+h], enc_b1[h])
__global__ __launch_bounds__(256) void gae_aux(
    const float* __restrict__ gcn2_w, const float* __restrict__ gcn2_b,
    const float* __restrict__ dec_w1, const float* __restrict__ dec_b1,
    const float* __restrict__ dec_w2, const float* __restrict__ enc_w1,
    const float* __restrict__ enc_b1, float* __restrict__ ws)
{
    const int tid = blockIdx.x * 256 + threadIdx.x;   // grid 8*256 = 2048
    const int f = tid >> 6, h = tid & 63;
    float acc = 0.0f;
    #pragma unroll 8
    for (int g = 0; g < 32; ++g)
        acc = fmaf(gcn2_w[f * 32 + g], dec_w1[g * 64 + h], acc);
    ws[f * 64 + h] = acc;
    if (tid < 64) {
        float c = dec_b1[h];
        #pragma unroll 8
        for (int g = 0; g < 32; ++g)
            c = fmaf(gcn2_b[g], dec_w1[g * 64 + h], c);
        ws[2048 + h] = c;
        ws[2112 + h] = dec_w2[h * 3 + 1];
    }
    if (tid < 512) {
        const int hh = tid >> 3, ii = tid & 7;
        ws[2176 + tid] = fmaf((float)ii, enc_w1[128 + hh], enc_b1[hh]);
    }
}

// Gabriel pair test, both directions. Op order identical to rounds 2-5.
template <int I, int J>
static __device__ __forceinline__ void gpair(const v2* __restrict__ p,
                                             unsigned& ml, unsigned& mh)
{
    #pragma clang fp contract(off)
    v2 mid = (p[I] + p[J]) * sp(0.5f);
    v2 di = p[I] - mid;  v2 si = di * di;  float r2i = si.x + si.y;
    v2 dj = p[J] - mid;  v2 sj = dj * dj;  float r2j = sj.x + sj.y;
    float dmin = 3.4e38f;
    #pragma unroll
    for (int k = 0; k < 8; ++k) {
        if (k == I || k == J) continue;
        v2 dk = p[k] - mid;
        v2 sk = dk * dk;
        dmin = fminf(dmin, sk.x + sk.y);
    }
    constexpr unsigned bi = 1u << (((I & 3) * 8) + J);  // row I, bit J
    constexpr unsigned bj = 1u << (((J & 3) * 8) + I);  // row J, bit I
    if (I < 4) ml |= (dmin < r2i) ? 0u : bi; else mh |= (dmin < r2i) ? 0u : bi;
    if (J < 4) ml |= (dmin < r2j) ? 0u : bj; else mh |= (dmin < r2j) ? 0u : bj;
}

__global__ __launch_bounds__(256, 8) void gae_main(
    const float* __restrict__ x,        // (B,8)
    const float* __restrict__ enc_w1,   // (3,64)
    const float* __restrict__ enc_w2,   // (64,2)
    const float* __restrict__ enc_b2,   // (2,)
    const float* __restrict__ gcn1_w,   // (2,32)
    const float* __restrict__ gcn1_b,   // (32,)
    const float* __restrict__ ws,       // folded tables (see gae_aux)
    const float* __restrict__ dec_b2,   // (3,)
    float* __restrict__ out_rec,        // (B,8)
    float* __restrict__ out_lat,        // (B,8,2)
    int B)
{
    __shared__ union { v2 p[8][64]; v2 t[16][64]; } ptb;            // 8 KB
    __shared__ union { unsigned m[4][2][64]; float o[4][64]; } mob; // 2 KB

    const int lane = threadIdx.x & 63;
    const int ru   = __builtin_amdgcn_readfirstlane(threadIdx.x >> 6); // 0..3
    int g = blockIdx.x * 64 + lane;
    if (g >= B) g = B - 1;

    // ---- load own 2 nodes' x (8B/lane, coalesced) ----
    const float2 xr = *reinterpret_cast<const float2*>(x + (size_t)g * 8 + 2 * ru);
    const v2 xp2 = (v2){xr.x, xr.y};

    // ---- encoder, own 2 nodes (nodes 2ru, 2ru+1); bit-identical math ----
    const float* ctab = ws + 2176;
    v2 pl0, pl1;
    { const v2 b2v = ldv2(enc_b2); pl0 = b2v; pl1 = b2v; }
    #pragma unroll 8
    for (int h = 0; h < 64; ++h) {
        const float wx = enc_w1[64 + h];
        const v2 uxy = ldv2(enc_w2 + 2 * h);
        const v2 cpr = ldv2(ctab + h * 8 + 2 * ru);   // fmaf(i,wi,bb) pair
        v2 t = fma2(xp2, sp(wx), cpr);
        float t0 = fmaxf(t.x, 0.0f);
        float t1 = fmaxf(t.y, 0.0f);
        pl0 = fma2(sp(t0), uxy, pl0);
        pl1 = fma2(sp(t1), uxy, pl1);
    }
    // (latent global store deferred to kernel end: avoids vmcnt drain at
    //  the barriers below.)

    // ---- exchange latent ----
    ptb.p[2 * ru + 0][lane] = pl0;
    ptb.p[2 * ru + 1][lane] = pl1;
    __syncthreads();
    v2 p[8];
    #pragma unroll
    for (int j = 0; j < 8; ++j) p[j] = ptb.p[j][lane];

    // ---- Gabriel, 7 pairs per role -> partial packed row masks ----
    unsigned ml = 0u, mh = 0u;
    if (ru == 0) {
        gpair<0,1>(p, ml, mh); gpair<0,2>(p, ml, mh); gpair<0,3>(p, ml, mh);
        gpair<0,4>(p, ml, mh); gpair<0,5>(p, ml, mh); gpair<0,6>(p, ml, mh);
        gpair<0,7>(p, ml, mh);
    } else if (ru == 1) {
        gpair<1,2>(p, ml, mh); gpair<1,3>(p, ml, mh); gpair<1,4>(p, ml, mh);
        gpair<1,5>(p, ml, mh); gpair<1,6>(p, ml, mh); gpair<1,7>(p, ml, mh);
        gpair<2,3>(p, ml, mh);
    } else if (ru == 2) {
        gpair<2,4>(p, ml, mh); gpair<2,5>(p, ml, mh); gpair<2,6>(p, ml, mh);
        gpair<2,7>(p, ml, mh); gpair<3,4>(p, ml, mh); gpair<3,5>(p, ml, mh);
        gpair<3,6>(p, ml, mh);
    } else {
        gpair<3,7>(p, ml, mh); gpair<4,5>(p, ml, mh); gpair<4,6>(p, ml, mh);
        gpair<4,7>(p, ml, mh); gpair<5,6>(p, ml, mh); gpair<5,7>(p, ml, mh);
        gpair<6,7>(p, ml, mh);
    }

    // ---- combine masks (+ self loops) ----
    mob.m[ru][0][lane] = ml;
    mob.m[ru][1][lane] = mh;
    __syncthreads();
    ml = (mob.m[0][0][lane] | mob.m[1][0][lane]) |
         (mob.m[2][0][lane] | mob.m[3][0][lane]) | 0x08040201u;
    mh = (mob.m[0][1][lane] | mob.m[1][1][lane]) |
         (mob.m[2][1][lane] | mob.m[3][1][lane]) | 0x80402010u;

    // ---- dinv[8], q[8], full n[8], cj[8] in registers (duplicated/role;
    //      formulas + accumulation order bit-identical to r5's split form) ----
    float dinv[8];
    v2 q[8];
    #pragma unroll
    for (int i = 0; i < 8; ++i) {
        const unsigned rb = ((i < 4 ? ml : mh) >> ((i & 3) * 8)) & 0xffu;
        dinv[i] = __builtin_amdgcn_rsqf((float)__popc(rb));
        q[i] = sp(dinv[i]) * p[i];
    }
    v2 n[8];
    #pragma unroll
    for (int i = 0; i < 8; ++i) {
        const unsigned rb = ((i < 4 ? ml : mh) >> ((i & 3) * 8)) & 0xffu;
        v2 acc = sp(0.0f);
        #pragma unroll
        for (int j = 0; j < 8; ++j)
            acc = fma2(sp((float)((rb >> j) & 1u)), q[j], acc);
        n[i] = sp(dinv[i]) * acc;
    }
    float cj[8];
    #pragma unroll
    for (int j = 0; j < 8; ++j) {
        float s = 0.0f;
        #pragma unroll
        for (int i = 0; i < 8; ++i) {
            const unsigned rb = ((i < 4 ? ml : mh) >> ((i & 3) * 8)) & 0xffu;
            s = fmaf((float)((rb >> j) & 1u), dinv[i], s);
        }
        cj[j] = 0.125f * dinv[j] * s;
    }

    // ---- GCN1 + pooled projection, own 8 features (f in [8ru, 8ru+8)) ----
    const float* w0 = gcn1_w + 8 * ru;
    const float* w1 = gcn1_w + 32 + 8 * ru;
    const float* bl = gcn1_b + 8 * ru;
    v2 t2[4];
    #pragma unroll
    for (int fp = 0; fp < 4; ++fp) t2[fp] = sp(0.0f);
    #pragma unroll
    for (int i = 0; i < 8; ++i) {
        const v2 nxi = sp(n[i].x), nyi = sp(n[i].y), civ = sp(cj[i]);
        #pragma unroll
        for (int fp = 0; fp < 4; ++fp) {
            v2 h = fma2(nxi, ldv2(w0 + 2 * fp),
                   fma2(nyi, ldv2(w1 + 2 * fp), ldv2(bl + 2 * fp)));
            h = __builtin_elementwise_max(h, sp(0.0f));
            t2[fp] = fma2(civ, h, t2[fp]);
        }
    }

    // ---- exchange t (reuses latent LDS; mask barrier separates p-reads) ----
    #pragma unroll
    for (int fp = 0; fp < 4; ++fp) ptb.t[4 * ru + fp][lane] = t2[fp];
    __syncthreads();

    // ---- folded decoder, own 16 h's: a_h = cdec_h + sum_f t_f Wdec[f][h] ----
    const float* Wd = ws + 16 * ru;           // row stride 64
    const float* cd = ws + 2048 + 16 * ru;
    const float* w2 = ws + 2112 + 16 * ru;
    v2 a2[8];
    #pragma unroll
    for (int hp = 0; hp < 8; ++hp) a2[hp] = ldv2(cd + 2 * hp);
    __builtin_amdgcn_s_setprio(1);
    #pragma unroll
    for (int fp = 0; fp < 16; ++fp) {
        const v2 tv = ptb.t[fp][lane];        // ds_read_b64
        const float* wrA = Wd + (2 * fp) * 64;
        const float* wrB = Wd + (2 * fp + 1) * 64;
        const v2 tA = sp(tv.x), tB = sp(tv.y);
        #pragma unroll
        for (int hp = 0; hp < 8; ++hp) {
            a2[hp] = fma2(tA, ldv2(wrA + 2 * hp), a2[hp]);
            a2[hp] = fma2(tB, ldv2(wrB + 2 * hp), a2[hp]);
        }
    }
    __builtin_amdgcn_s_setprio(0);
    v2 oacc = sp(0.0f);
    #pragma unroll
    for (int hp = 0; hp < 8; ++hp) {
        v2 rr = __builtin_elementwise_max(a2[hp], sp(0.0f));
        oacc = fma2(rr, ldv2(w2 + 2 * hp), oacc);
    }
    const float opart = oacc.x + oacc.y;

    // ---- combine 4 partials (same order on all roles -> identical bits) ----
    mob.o[ru][lane] = opart;                  // mask region dead since GCN1
    __syncthreads();
    const float outv = ((mob.o[0][lane] + mob.o[1][lane]) +
                        (mob.o[2][lane] + mob.o[3][lane])) + dec_b2[1];

    // ---- all global stores at the end ----
    *reinterpret_cast<float4*>(out_lat + (size_t)g * 16 + 4 * ru) =
        make_float4(pl0.x, pl0.y, pl1.x, pl1.y);
    *reinterpret_cast<float2*>(out_rec + (size_t)g * 8 + 2 * ru) =
        make_float2(outv, outv);
}

extern "C" void kernel_launch(void* const* d_in, const int* in_sizes, int n_in,
                              void* d_out, int out_size, void* d_ws, size_t ws_size,
                              hipStream_t stream) {
    const float* x       = (const float*)d_in[0];
    const float* enc_w1  = (const float*)d_in[1];
    const float* enc_b1  = (const float*)d_in[2];
    const float* enc_w2  = (const float*)d_in[3];
    const float* enc_b2  = (const float*)d_in[4];
    const float* gcn1_w  = (const float*)d_in[5];
    const float* gcn1_b  = (const float*)d_in[6];
    const float* gcn2_w  = (const float*)d_in[7];
    const float* gcn2_b  = (const float*)d_in[8];
    const float* dec_w1  = (const float*)d_in[9];
    const float* dec_b1  = (const float*)d_in[10];
    const float* dec_w2  = (const float*)d_in[11];
    const float* dec_b2  = (const float*)d_in[12];

    const int B = in_sizes[0] / 8;
    float* out_rec = (float*)d_out;                 // (B,8)
    float* out_lat = out_rec + (size_t)B * 8;       // (B,8,2)
    float* ws      = (float*)d_ws;                  // needs 2688 floats

    gae_aux<<<8, 256, 0, stream>>>(gcn2_w, gcn2_b, dec_w1, dec_b1, dec_w2,
                                   enc_w1, enc_b1, ws);

    const int blocks = (B + 63) / 64;               // 64 graphs per block
    gae_main<<<blocks, 256, 0, stream>>>(
        x, enc_w1, enc_w2, enc_b2,
        gcn1_w, gcn1_b, ws, dec_b2,
        out_rec, out_lat, B);
}

// Round 7
// 109.503 us; speedup vs baseline: 1.4938x; 1.4938x over previous
//
#include <hip/hip_runtime.h>

// GraphAutoEncoder, two-kernel split (B=131072, N=8):
//   gae_enc: streaming encoder, 4 threads/graph (2 nodes each), no LDS/barriers,
//            writes latent (also the 2nd output). Bit-exact vs rounds 2-6.
//   gae_gcn: 4 role-waves/graph (wave w = role w, lane L = graph), reads latent
//            from global (L1-hot), Gabriel 7 pairs/role, GCN algebraically
//            reduced, folded decoder. 4 barriers, 16 KB LDS, fits 64-VGPR cap
//            of __launch_bounds__(256,8)  (r6 lesson: r5's duplicated n/cj
//            spilled to scratch -> 229 MB writes; this keeps r4's split shape).
//   gae_aux: folds gcn2_w @ dec_w1 (+bias, +dec_w2[:,1]) into d_ws.

typedef float v2 __attribute__((ext_vector_type(2)));
static __device__ __forceinline__ v2 sp(float s) { return (v2){s, s}; }
static __device__ __forceinline__ v2 fma2(v2 a, v2 b, v2 c) {
    return __builtin_elementwise_fma(a, b, c);
}
static __device__ __forceinline__ v2 ldv2(const float* p) {
    return *reinterpret_cast<const v2*>(p);
}

// ws layout (floats):
//   [0,2048)    Wdec[32][64] = gcn2_w @ dec_w1
//   [2048,2112) cdec[64]     = gcn2_b @ dec_w1 + dec_b1
//   [2112,2176) w2col[64]    = dec_w2[:,1]
__global__ __launch_bounds__(256) void gae_aux(
    const float* __restrict__ gcn2_w, const float* __restrict__ gcn2_b,
    const float* __restrict__ dec_w1, const float* __restrict__ dec_b1,
    const float* __restrict__ dec_w2, float* __restrict__ ws)
{
    const int tid = blockIdx.x * 256 + threadIdx.x;   // grid 8*256 = 2048
    const int f = tid >> 6, h = tid & 63;
    float acc = 0.0f;
    #pragma unroll 8
    for (int g = 0; g < 32; ++g)
        acc = fmaf(gcn2_w[f * 32 + g], dec_w1[g * 64 + h], acc);
    ws[f * 64 + h] = acc;
    if (tid < 64) {
        float c = dec_b1[h];
        #pragma unroll 8
        for (int g = 0; g < 32; ++g)
            c = fmaf(gcn2_b[g], dec_w1[g * 64 + h], c);
        ws[2048 + h] = c;
        ws[2112 + h] = dec_w2[h * 3 + 1];
    }
}

// ---- k1: encoder. thread t = (graph g = t>>2, role ru = t&3), nodes 2ru,2ru+1.
// x read = 8B/lane contiguous; latent write = 16B/lane contiguous.
__global__ __launch_bounds__(256, 8) void gae_enc(
    const float* __restrict__ x,        // (B,8)
    const float* __restrict__ enc_w1,   // (3,64)
    const float* __restrict__ enc_b1,   // (64,)
    const float* __restrict__ enc_w2,   // (64,2)
    const float* __restrict__ enc_b2,   // (2,)
    float* __restrict__ out_lat,        // (B,8,2)
    int nthreads)
{
    const int t = blockIdx.x * 256 + threadIdx.x;
    if (t >= nthreads) return;

    const float2 xr = *reinterpret_cast<const float2*>(x + (size_t)t * 2);
    const v2 xp2 = (v2){xr.x, xr.y};
    const float i0 = (float)(2 * (t & 3));
    const float i1 = i0 + 1.0f;

    v2 pl0, pl1;
    { const v2 b2v = ldv2(enc_b2); pl0 = b2v; pl1 = b2v; }
    #pragma unroll 8
    for (int h = 0; h < 64; ++h) {
        const float wx = enc_w1[64 + h];
        const float wi = enc_w1[128 + h];
        const float bb = enc_b1[h];
        const v2 uxy = ldv2(enc_w2 + 2 * h);
        // c = fmaf(i, wi, bb): identical fma sequence to all passing rounds.
        const float c0 = fmaf(i0, wi, bb);
        const float c1 = fmaf(i1, wi, bb);
        v2 tt = fma2(xp2, sp(wx), (v2){c0, c1});
        float t0 = fmaxf(tt.x, 0.0f);
        float t1 = fmaxf(tt.y, 0.0f);
        pl0 = fma2(sp(t0), uxy, pl0);
        pl1 = fma2(sp(t1), uxy, pl1);
    }
    *reinterpret_cast<float4*>(out_lat + (size_t)t * 4) =
        make_float4(pl0.x, pl0.y, pl1.x, pl1.y);
}

// Gabriel pair test, both directions. Op order identical to rounds 2-6.
template <int I, int J>
static __device__ __forceinline__ void gpair(const v2* __restrict__ p,
                                             unsigned& ml, unsigned& mh)
{
    #pragma clang fp contract(off)
    v2 mid = (p[I] + p[J]) * sp(0.5f);
    v2 di = p[I] - mid;  v2 si = di * di;  float r2i = si.x + si.y;
    v2 dj = p[J] - mid;  v2 sj = dj * dj;  float r2j = sj.x + sj.y;
    float dmin = 3.4e38f;
    #pragma unroll
    for (int k = 0; k < 8; ++k) {
        if (k == I || k == J) continue;
        v2 dk = p[k] - mid;
        v2 sk = dk * dk;
        dmin = fminf(dmin, sk.x + sk.y);
    }
    constexpr unsigned bi = 1u << (((I & 3) * 8) + J);  // row I, bit J
    constexpr unsigned bj = 1u << (((J & 3) * 8) + I);  // row J, bit I
    if (I < 4) ml |= (dmin < r2i) ? 0u : bi; else mh |= (dmin < r2i) ? 0u : bi;
    if (J < 4) ml |= (dmin < r2j) ? 0u : bj; else mh |= (dmin < r2j) ? 0u : bj;
}

// ---- k2: graph + GCN + decoder. wave w = role w; lane L = graph g.
__global__ __launch_bounds__(256, 8) void gae_gcn(
    const float* __restrict__ lat,      // (B,8,2) = out_lat written by gae_enc
    const float* __restrict__ gcn1_w,   // (2,32)
    const float* __restrict__ gcn1_b,   // (32,)
    const float* __restrict__ ws,       // folded tables (see gae_aux)
    const float* __restrict__ dec_b2,   // (3,)
    float* __restrict__ out_rec,        // (B,8)
    int B)
{
    __shared__ v2 tbuf[16][64];                                     // 8 KB
    __shared__ unsigned mbuf[4][2][64];                             // 2 KB
    __shared__ union { struct { v2 n[8][64]; float cj[8][64]; } nc; // 6 KB
                       float o[4][64]; } u;

    const int lane = threadIdx.x & 63;
    const int ru   = __builtin_amdgcn_readfirstlane(threadIdx.x >> 6); // 0..3
    int g = blockIdx.x * 64 + lane;
    if (g >= B) g = B - 1;

    // ---- load all 8 latent points (64B; 4 role-waves share -> L1) ----
    v2 p[8];
    {
        const float4* lp = reinterpret_cast<const float4*>(lat + (size_t)g * 16);
        float4 a = lp[0], b = lp[1], c = lp[2], d = lp[3];
        p[0] = (v2){a.x, a.y}; p[1] = (v2){a.z, a.w};
        p[2] = (v2){b.x, b.y}; p[3] = (v2){b.z, b.w};
        p[4] = (v2){c.x, c.y}; p[5] = (v2){c.z, c.w};
        p[6] = (v2){d.x, d.y}; p[7] = (v2){d.z, d.w};
    }

    // ---- Gabriel, 7 pairs per role -> partial packed row masks ----
    unsigned ml = 0u, mh = 0u;
    if (ru == 0) {
        gpair<0,1>(p, ml, mh); gpair<0,2>(p, ml, mh); gpair<0,3>(p, ml, mh);
        gpair<0,4>(p, ml, mh); gpair<0,5>(p, ml, mh); gpair<0,6>(p, ml, mh);
        gpair<0,7>(p, ml, mh);
    } else if (ru == 1) {
        gpair<1,2>(p, ml, mh); gpair<1,3>(p, ml, mh); gpair<1,4>(p, ml, mh);
        gpair<1,5>(p, ml, mh); gpair<1,6>(p, ml, mh); gpair<1,7>(p, ml, mh);
        gpair<2,3>(p, ml, mh);
    } else if (ru == 2) {
        gpair<2,4>(p, ml, mh); gpair<2,5>(p, ml, mh); gpair<2,6>(p, ml, mh);
        gpair<2,7>(p, ml, mh); gpair<3,4>(p, ml, mh); gpair<3,5>(p, ml, mh);
        gpair<3,6>(p, ml, mh);
    } else {
        gpair<3,7>(p, ml, mh); gpair<4,5>(p, ml, mh); gpair<4,6>(p, ml, mh);
        gpair<4,7>(p, ml, mh); gpair<5,6>(p, ml, mh); gpair<5,7>(p, ml, mh);
        gpair<6,7>(p, ml, mh);
    }

    // ---- combine masks (+ self loops) ----
    mbuf[ru][0][lane] = ml;
    mbuf[ru][1][lane] = mh;
    __syncthreads();                                        // barrier 1
    ml = (mbuf[0][0][lane] | mbuf[1][0][lane]) |
         (mbuf[2][0][lane] | mbuf[3][0][lane]) | 0x08040201u;
    mh = (mbuf[0][1][lane] | mbuf[1][1][lane]) |
         (mbuf[2][1][lane] | mbuf[3][1][lane]) | 0x80402010u;

    // ---- dinv[8], q[8] (compile-time indexed -> registers) ----
    float dinv[8];
    v2 q[8];
    #pragma unroll
    for (int i = 0; i < 8; ++i) {
        const unsigned rb = ((i < 4 ? ml : mh) >> ((i & 3) * 8)) & 0xffu;
        dinv[i] = __builtin_amdgcn_rsqf((float)__popc(rb));
        q[i] = sp(dinv[i]) * p[i];
    }

    // ---- own 2 rows of n, own 2 cols of cj; publish to LDS (r4 shape) ----
    {
        const unsigned w = (ru < 2) ? ml : mh;
        const int sh = ((2 * ru) & 3) * 8;
        const unsigned rb0 = (w >> sh) & 0xffu;
        const unsigned rb1 = (w >> (sh + 8)) & 0xffu;
        const float dv0 = __builtin_amdgcn_rsqf((float)__popc(rb0));
        const float dv1 = __builtin_amdgcn_rsqf((float)__popc(rb1));
        v2 a0 = sp(0.0f), a1 = sp(0.0f);
        #pragma unroll
        for (int j = 0; j < 8; ++j) {
            a0 = fma2(sp((float)((rb0 >> j) & 1u)), q[j], a0);
            a1 = fma2(sp((float)((rb1 >> j) & 1u)), q[j], a1);
        }
        u.nc.n[2 * ru + 0][lane] = sp(dv0) * a0;
        u.nc.n[2 * ru + 1][lane] = sp(dv1) * a1;

        const int j0 = 2 * ru, j1 = 2 * ru + 1;
        float s0 = 0.0f, s1 = 0.0f;
        #pragma unroll
        for (int i = 0; i < 8; ++i) {
            const unsigned rb = ((i < 4 ? ml : mh) >> ((i & 3) * 8)) & 0xffu;
            s0 = fmaf((float)((rb >> j0) & 1u), dinv[i], s0);
            s1 = fmaf((float)((rb >> j1) & 1u), dinv[i], s1);
        }
        u.nc.cj[j0][lane] = 0.125f * dv0 * s0;
        u.nc.cj[j1][lane] = 0.125f * dv1 * s1;
    }
    __syncthreads();                                        // barrier 2

    // ---- GCN1 + pooled projection, own 8 features (f in [8ru, 8ru+8)) ----
    const float* w0 = gcn1_w + 8 * ru;
    const float* w1 = gcn1_w + 32 + 8 * ru;
    const float* bl = gcn1_b + 8 * ru;
    v2 t2[4];
    #pragma unroll
    for (int fp = 0; fp < 4; ++fp) t2[fp] = sp(0.0f);
    #pragma unroll
    for (int i = 0; i < 8; ++i) {
        const v2 ni = u.nc.n[i][lane];        // ds_read_b64
        const float ci = u.nc.cj[i][lane];    // ds_read_b32
        const v2 nxi = sp(ni.x), nyi = sp(ni.y), civ = sp(ci);
        #pragma unroll
        for (int fp = 0; fp < 4; ++fp) {
            v2 h = fma2(nxi, ldv2(w0 + 2 * fp),
                   fma2(nyi, ldv2(w1 + 2 * fp), ldv2(bl + 2 * fp)));
            h = __builtin_elementwise_max(h, sp(0.0f));
            t2[fp] = fma2(civ, h, t2[fp]);
        }
    }

    // ---- exchange t ----
    #pragma unroll
    for (int fp = 0; fp < 4; ++fp) tbuf[4 * ru + fp][lane] = t2[fp];
    __syncthreads();                                        // barrier 3

    // ---- folded decoder, own 16 h's: a_h = cdec_h + sum_f t_f Wdec[f][h] ----
    const float* Wd = ws + 16 * ru;           // row stride 64
    const float* cd = ws + 2048 + 16 * ru;
    const float* w2 = ws + 2112 + 16 * ru;
    v2 a2[8];
    #pragma unroll
    for (int hp = 0; hp < 8; ++hp) a2[hp] = ldv2(cd + 2 * hp);
    __builtin_amdgcn_s_setprio(1);
    #pragma unroll
    for (int fp = 0; fp < 16; ++fp) {
        const v2 tv = tbuf[fp][lane];         // ds_read_b64
        const float* wrA = Wd + (2 * fp) * 64;
        const float* wrB = Wd + (2 * fp + 1) * 64;
        const v2 tA = sp(tv.x), tB = sp(tv.y);
        #pragma unroll
        for (int hp = 0; hp < 8; ++hp) {
            a2[hp] = fma2(tA, ldv2(wrA + 2 * hp), a2[hp]);
            a2[hp] = fma2(tB, ldv2(wrB + 2 * hp), a2[hp]);
        }
    }
    __builtin_amdgcn_s_setprio(0);
    v2 oacc = sp(0.0f);
    #pragma unroll
    for (int hp = 0; hp < 8; ++hp) {
        v2 rr = __builtin_elementwise_max(a2[hp], sp(0.0f));
        oacc = fma2(rr, ldv2(w2 + 2 * hp), oacc);
    }
    const float opart = oacc.x + oacc.y;

    // ---- combine 4 partials (same order on all roles -> identical bits) ----
    u.o[ru][lane] = opart;                    // nc region dead since GCN1 reads
    __syncthreads();                                        // barrier 4
    const float outv = ((u.o[0][lane] + u.o[1][lane]) +
                        (u.o[2][lane] + u.o[3][lane])) + dec_b2[1];

    // ---- write reconstructed, own 2 nodes (8B/lane) ----
    *reinterpret_cast<float2*>(out_rec + (size_t)g * 8 + 2 * ru) =
        make_float2(outv, outv);
}

extern "C" void kernel_launch(void* const* d_in, const int* in_sizes, int n_in,
                              void* d_out, int out_size, void* d_ws, size_t ws_size,
                              hipStream_t stream) {
    const float* x       = (const float*)d_in[0];
    const float* enc_w1  = (const float*)d_in[1];
    const float* enc_b1  = (const float*)d_in[2];
    const float* enc_w2  = (const float*)d_in[3];
    const float* enc_b2  = (const float*)d_in[4];
    const float* gcn1_w  = (const float*)d_in[5];
    const float* gcn1_b  = (const float*)d_in[6];
    const float* gcn2_w  = (const float*)d_in[7];
    const float* gcn2_b  = (const float*)d_in[8];
    const float* dec_w1  = (const float*)d_in[9];
    const float* dec_b1  = (const float*)d_in[10];
    const float* dec_w2  = (const float*)d_in[11];
    const float* dec_b2  = (const float*)d_in[12];

    const int B = in_sizes[0] / 8;
    float* out_rec = (float*)d_out;                 // (B,8)
    float* out_lat = out_rec + (size_t)B * 8;       // (B,8,2)
    float* ws      = (float*)d_ws;                  // needs 2176 floats

    gae_aux<<<8, 256, 0, stream>>>(gcn2_w, gcn2_b, dec_w1, dec_b1, dec_w2, ws);

    const int nthreads = 4 * B;                     // 4 threads per graph
    gae_enc<<<(nthreads + 255) / 256, 256, 0, stream>>>(
        x, enc_w1, enc_b1, enc_w2, enc_b2, out_lat, nthreads);

    const int blocks = (B + 63) / 64;               // 64 graphs per block
    gae_gcn<<<blocks, 256, 0, stream>>>(
        out_lat, gcn1_w, gcn1_b, ws, dec_b2, out_rec, B);
}

// Round 8
// 106.679 us; speedup vs baseline: 1.5333x; 1.0265x over previous
//
#include <hip/hip_runtime.h>

// GraphAutoEncoder: FOUR threads per graph (B=131072, N=8), one role per wave
// (wave w of block handles role w; lane L of all 4 waves = graph g).
// Structure = round-4 kernel (measured best, 107.0): encoder 2 nodes/role,
// Gabriel 7 pairs/role, n/cj 2 rows/cols per role published via LDS, GCN1 8
// features/role, folded decoder 16 h/role. 5 barriers, 16 KB LDS,
// __launch_bounds__(256,8) -> 8 blocks/CU.
// Deltas vs r4: (1) global stores deferred past the last barrier (no vmcnt
// drain at barriers), (2) s_setprio(1) around decoder FMA cluster.
// All decision + accumulation arithmetic bit-identical to rounds 2-7.

typedef float v2 __attribute__((ext_vector_type(2)));
static __device__ __forceinline__ v2 sp(float s) { return (v2){s, s}; }
static __device__ __forceinline__ v2 fma2(v2 a, v2 b, v2 c) {
    return __builtin_elementwise_fma(a, b, c);
}
static __device__ __forceinline__ v2 ldv2(const float* p) {
    return *reinterpret_cast<const v2*>(p);
}

// ws layout (floats):
//   [0,2048)    Wdec[32][64] = gcn2_w @ dec_w1
//   [2048,2112) cdec[64]     = gcn2_b @ dec_w1 + dec_b1
//   [2112,2176) w2col[64]    = dec_w2[:,1]
//   [2176,2688) ctab[64][8]  : ctab[h*8+i] = fmaf(i, enc_w1[128+h], enc_b1[h])
__global__ __launch_bounds__(256) void gae_aux(
    const float* __restrict__ gcn2_w, const float* __restrict__ gcn2_b,
    const float* __restrict__ dec_w1, const float* __restrict__ dec_b1,
    const float* __restrict__ dec_w2, const float* __restrict__ enc_w1,
    const float* __restrict__ enc_b1, float* __restrict__ ws)
{
    const int tid = blockIdx.x * 256 + threadIdx.x;   // grid 8*256 = 2048
    const int f = tid >> 6, h = tid & 63;
    float acc = 0.0f;
    #pragma unroll 8
    for (int g = 0; g < 32; ++g)
        acc = fmaf(gcn2_w[f * 32 + g], dec_w1[g * 64 + h], acc);
    ws[f * 64 + h] = acc;
    if (tid < 64) {
        float c = dec_b1[h];
        #pragma unroll 8
        for (int g = 0; g < 32; ++g)
            c = fmaf(gcn2_b[g], dec_w1[g * 64 + h], c);
        ws[2048 + h] = c;
        ws[2112 + h] = dec_w2[h * 3 + 1];
    }
    if (tid < 512) {
        const int hh = tid >> 3, ii = tid & 7;
        ws[2176 + tid] = fmaf((float)ii, enc_w1[128 + hh], enc_b1[hh]);
    }
}

// Gabriel pair test, both directions. Op order identical to rounds 2-7.
template <int I, int J>
static __device__ __forceinline__ void gpair(const v2* __restrict__ p,
                                             unsigned& ml, unsigned& mh)
{
    #pragma clang fp contract(off)
    v2 mid = (p[I] + p[J]) * sp(0.5f);
    v2 di = p[I] - mid;  v2 si = di * di;  float r2i = si.x + si.y;
    v2 dj = p[J] - mid;  v2 sj = dj * dj;  float r2j = sj.x + sj.y;
    float dmin = 3.4e38f;
    #pragma unroll
    for (int k = 0; k < 8; ++k) {
        if (k == I || k == J) continue;
        v2 dk = p[k] - mid;
        v2 sk = dk * dk;
        dmin = fminf(dmin, sk.x + sk.y);
    }
    constexpr unsigned bi = 1u << (((I & 3) * 8) + J);  // row I, bit J
    constexpr unsigned bj = 1u << (((J & 3) * 8) + I);  // row J, bit I
    if (I < 4) ml |= (dmin < r2i) ? 0u : bi; else mh |= (dmin < r2i) ? 0u : bi;
    if (J < 4) ml |= (dmin < r2j) ? 0u : bj; else mh |= (dmin < r2j) ? 0u : bj;
}

__global__ __launch_bounds__(256, 8) void gae_main(
    const float* __restrict__ x,        // (B,8)
    const float* __restrict__ enc_w1,   // (3,64)
    const float* __restrict__ enc_w2,   // (64,2)
    const float* __restrict__ enc_b2,   // (2,)
    const float* __restrict__ gcn1_w,   // (2,32)
    const float* __restrict__ gcn1_b,   // (32,)
    const float* __restrict__ ws,       // folded tables (see gae_aux)
    const float* __restrict__ dec_b2,   // (3,)
    float* __restrict__ out_rec,        // (B,8)
    float* __restrict__ out_lat,        // (B,8,2)
    int B)
{
    __shared__ union { v2 p[8][64]; v2 t[16][64]; } ptb;            // 8 KB
    __shared__ union { unsigned m[4][2][64]; float o[4][64]; } mob; // 2 KB
    __shared__ v2    nbuf[8][64];                                  // 4 KB
    __shared__ float cjbuf[8][64];                                 // 2 KB

    const int lane = threadIdx.x & 63;
    const int ru   = __builtin_amdgcn_readfirstlane(threadIdx.x >> 6); // 0..3
    int g = blockIdx.x * 64 + lane;
    if (g >= B) g = B - 1;

    // ---- load own 2 nodes' x (8B/lane, coalesced) ----
    const float2 xr = *reinterpret_cast<const float2*>(x + (size_t)g * 8 + 2 * ru);
    const v2 xp2 = (v2){xr.x, xr.y};

    // ---- encoder, own 2 nodes (nodes 2ru, 2ru+1); bit-identical math ----
    const float* ctab = ws + 2176;
    v2 pl0, pl1;
    { const v2 b2v = ldv2(enc_b2); pl0 = b2v; pl1 = b2v; }
    #pragma unroll 8
    for (int h = 0; h < 64; ++h) {
        const float wx = enc_w1[64 + h];
        const v2 uxy = ldv2(enc_w2 + 2 * h);
        const v2 cpr = ldv2(ctab + h * 8 + 2 * ru);   // fmaf(i,wi,bb) pair
        v2 t = fma2(xp2, sp(wx), cpr);
        float t0 = fmaxf(t.x, 0.0f);
        float t1 = fmaxf(t.y, 0.0f);
        pl0 = fma2(sp(t0), uxy, pl0);
        pl1 = fma2(sp(t1), uxy, pl1);
    }
    // (latent store deferred to kernel end: no vmcnt drain at the barriers)

    // ---- exchange latent ----
    ptb.p[2 * ru + 0][lane] = pl0;
    ptb.p[2 * ru + 1][lane] = pl1;
    __syncthreads();                                        // barrier 1
    v2 p[8];
    #pragma unroll
    for (int j = 0; j < 8; ++j) p[j] = ptb.p[j][lane];

    // ---- Gabriel, 7 pairs per role -> partial packed row masks ----
    unsigned ml = 0u, mh = 0u;
    if (ru == 0) {
        gpair<0,1>(p, ml, mh); gpair<0,2>(p, ml, mh); gpair<0,3>(p, ml, mh);
        gpair<0,4>(p, ml, mh); gpair<0,5>(p, ml, mh); gpair<0,6>(p, ml, mh);
        gpair<0,7>(p, ml, mh);
    } else if (ru == 1) {
        gpair<1,2>(p, ml, mh); gpair<1,3>(p, ml, mh); gpair<1,4>(p, ml, mh);
        gpair<1,5>(p, ml, mh); gpair<1,6>(p, ml, mh); gpair<1,7>(p, ml, mh);
        gpair<2,3>(p, ml, mh);
    } else if (ru == 2) {
        gpair<2,4>(p, ml, mh); gpair<2,5>(p, ml, mh); gpair<2,6>(p, ml, mh);
        gpair<2,7>(p, ml, mh); gpair<3,4>(p, ml, mh); gpair<3,5>(p, ml, mh);
        gpair<3,6>(p, ml, mh);
    } else {
        gpair<3,7>(p, ml, mh); gpair<4,5>(p, ml, mh); gpair<4,6>(p, ml, mh);
        gpair<4,7>(p, ml, mh); gpair<5,6>(p, ml, mh); gpair<5,7>(p, ml, mh);
        gpair<6,7>(p, ml, mh);
    }

    // ---- combine masks (+ self loops) ----
    mob.m[ru][0][lane] = ml;
    mob.m[ru][1][lane] = mh;
    __syncthreads();                                        // barrier 2
    ml = (mob.m[0][0][lane] | mob.m[1][0][lane]) |
         (mob.m[2][0][lane] | mob.m[3][0][lane]) | 0x08040201u;
    mh = (mob.m[0][1][lane] | mob.m[1][1][lane]) |
         (mob.m[2][1][lane] | mob.m[3][1][lane]) | 0x80402010u;

    // ---- dinv[8], q[8] (all compile-time indexed -> stays in regs) ----
    float dinv[8];
    v2 q[8];
    #pragma unroll
    for (int i = 0; i < 8; ++i) {
        const unsigned rb = ((i < 4 ? ml : mh) >> ((i & 3) * 8)) & 0xffu;
        dinv[i] = __builtin_amdgcn_rsqf((float)__popc(rb));
        q[i] = sp(dinv[i]) * p[i];
    }

    // ---- own 2 rows of n, own 2 cols of cj; publish to LDS (r4 shape) ----
    {
        const unsigned w = (ru < 2) ? ml : mh;
        const int sh = ((2 * ru) & 3) * 8;
        const unsigned rb0 = (w >> sh) & 0xffu;
        const unsigned rb1 = (w >> (sh + 8)) & 0xffu;
        const float dv0 = __builtin_amdgcn_rsqf((float)__popc(rb0));
        const float dv1 = __builtin_amdgcn_rsqf((float)__popc(rb1));
        v2 a0 = sp(0.0f), a1 = sp(0.0f);
        #pragma unroll
        for (int j = 0; j < 8; ++j) {
            a0 = fma2(sp((float)((rb0 >> j) & 1u)), q[j], a0);
            a1 = fma2(sp((float)((rb1 >> j) & 1u)), q[j], a1);
        }
        nbuf[2 * ru + 0][lane] = sp(dv0) * a0;
        nbuf[2 * ru + 1][lane] = sp(dv1) * a1;

        const int j0 = 2 * ru, j1 = 2 * ru + 1;
        float s0 = 0.0f, s1 = 0.0f;
        #pragma unroll
        for (int i = 0; i < 8; ++i) {
            const unsigned rb = ((i < 4 ? ml : mh) >> ((i & 3) * 8)) & 0xffu;
            s0 = fmaf((float)((rb >> j0) & 1u), dinv[i], s0);
            s1 = fmaf((float)((rb >> j1) & 1u), dinv[i], s1);
        }
        cjbuf[j0][lane] = 0.125f * dv0 * s0;
        cjbuf[j1][lane] = 0.125f * dv1 * s1;
    }
    __syncthreads();                                        // barrier 3

    // ---- GCN1 + pooled projection, own 8 features (f in [8ru, 8ru+8)) ----
    const float* w0 = gcn1_w + 8 * ru;
    const float* w1 = gcn1_w + 32 + 8 * ru;
    const float* bl = gcn1_b + 8 * ru;
    v2 t2[4];
    #pragma unroll
    for (int fp = 0; fp < 4; ++fp) t2[fp] = sp(0.0f);
    #pragma unroll
    for (int i = 0; i < 8; ++i) {
        const v2 ni = nbuf[i][lane];          // ds_read_b64
        const float ci = cjbuf[i][lane];      // ds_read_b32
        const v2 nxi = sp(ni.x), nyi = sp(ni.y), civ = sp(ci);
        #pragma unroll
        for (int fp = 0; fp < 4; ++fp) {
            v2 h = fma2(nxi, ldv2(w0 + 2 * fp),
                   fma2(nyi, ldv2(w1 + 2 * fp), ldv2(bl + 2 * fp)));
            h = __builtin_elementwise_max(h, sp(0.0f));
            t2[fp] = fma2(civ, h, t2[fp]);
        }
    }

    // ---- exchange t (reuses latent LDS; mask barrier separates p-reads) ----
    #pragma unroll
    for (int fp = 0; fp < 4; ++fp) ptb.t[4 * ru + fp][lane] = t2[fp];
    __syncthreads();                                        // barrier 4

    // ---- folded decoder, own 16 h's: a_h = cdec_h + sum_f t_f Wdec[f][h] ----
    const float* Wd = ws + 16 * ru;           // row stride 64
    const float* cd = ws + 2048 + 16 * ru;
    const float* w2 = ws + 2112 + 16 * ru;
    v2 a2[8];
    #pragma unroll
    for (int hp = 0; hp < 8; ++hp) a2[hp] = ldv2(cd + 2 * hp);
    __builtin_amdgcn_s_setprio(1);
    #pragma unroll
    for (int fp = 0; fp < 16; ++fp) {
        const v2 tv = ptb.t[fp][lane];        // ds_read_b64
        const float* wrA = Wd + (2 * fp) * 64;
        const float* wrB = Wd + (2 * fp + 1) * 64;
        const v2 tA = sp(tv.x), tB = sp(tv.y);
        #pragma unroll
        for (int hp = 0; hp < 8; ++hp) {
            a2[hp] = fma2(tA, ldv2(wrA + 2 * hp), a2[hp]);
            a2[hp] = fma2(tB, ldv2(wrB + 2 * hp), a2[hp]);
        }
    }
    __builtin_amdgcn_s_setprio(0);
    v2 oacc = sp(0.0f);
    #pragma unroll
    for (int hp = 0; hp < 8; ++hp) {
        v2 rr = __builtin_elementwise_max(a2[hp], sp(0.0f));
        oacc = fma2(rr, ldv2(w2 + 2 * hp), oacc);
    }
    const float opart = oacc.x + oacc.y;

    // ---- combine 4 partials (same order on all roles -> identical bits) ----
    mob.o[ru][lane] = opart;                  // mask region dead since GCN1
    __syncthreads();                                        // barrier 5
    const float outv = ((mob.o[0][lane] + mob.o[1][lane]) +
                        (mob.o[2][lane] + mob.o[3][lane])) + dec_b2[1];

    // ---- all global stores after the last barrier ----
    *reinterpret_cast<float4*>(out_lat + (size_t)g * 16 + 4 * ru) =
        make_float4(pl0.x, pl0.y, pl1.x, pl1.y);
    *reinterpret_cast<float2*>(out_rec + (size_t)g * 8 + 2 * ru) =
        make_float2(outv, outv);
}

extern "C" void kernel_launch(void* const* d_in, const int* in_sizes, int n_in,
                              void* d_out, int out_size, void* d_ws, size_t ws_size,
                              hipStream_t stream) {
    const float* x       = (const float*)d_in[0];
    const float* enc_w1  = (const float*)d_in[1];
    const float* enc_b1  = (const float*)d_in[2];
    const float* enc_w2  = (const float*)d_in[3];
    const float* enc_b2  = (const float*)d_in[4];
    const float* gcn1_w  = (const float*)d_in[5];
    const float* gcn1_b  = (const float*)d_in[6];
    const float* gcn2_w  = (const float*)d_in[7];
    const float* gcn2_b  = (const float*)d_in[8];
    const float* dec_w1  = (const float*)d_in[9];
    const float* dec_b1  = (const float*)d_in[10];
    const float* dec_w2  = (const float*)d_in[11];
    const float* dec_b2  = (const float*)d_in[12];

    const int B = in_sizes[0] / 8;
    float* out_rec = (float*)d_out;                 // (B,8)
    float* out_lat = out_rec + (size_t)B * 8;       // (B,8,2)
    float* ws      = (float*)d_ws;                  // needs 2688 floats

    gae_aux<<<8, 256, 0, stream>>>(gcn2_w, gcn2_b, dec_w1, dec_b1, dec_w2,
                                   enc_w1, enc_b1, ws);

    const int blocks = (B + 63) / 64;               // 64 graphs per block
    gae_main<<<blocks, 256, 0, stream>>>(
        x, enc_w1, enc_w2, enc_b2,
        gcn1_w, gcn1_b, ws, dec_b2,
        out_rec, out_lat, B);
}

// Round 9
// 106.060 us; speedup vs baseline: 1.5423x; 1.0058x over previous
//
#include <hip/hip_runtime.h>

// GraphAutoEncoder, SINGLE kernel (B=131072, N=8). Four threads per graph,
// one role per wave (wave w = role w; lane L = graph g of the block).
// Role split: encoder 2 nodes, Gabriel 7 pairs, n/cj 2 rows/cols via LDS,
// GCN1 8 features, pooled 8 g's, decoder 16 h's. 6 barriers.
// vs r8: gae_aux dispatch removed — decoder runs UNFOLDED (pooled stage
// restored, bit-proven in r2/r3), encoder c inline (bit-proven in r7).
// 16 KB LDS arena, phase-aliased (all windows barrier-separated):
//   floats [0,2048)    : p[8][64]v2 -> t[16][64]v2 -> o[4][64]
//   floats [2048,2560) : masks[4][2][64]u32 -> pooled rows 0..7
//   floats [2560,4096) : n[8][64]v2 + cj[8][64] -> pooled rows 8..31
// __launch_bounds__(256,8): 8 blocks/CU, 128 KB LDS/CU, 32 waves/CU (cap).
// All decision + accumulation arithmetic bit-identical to passing rounds.

typedef float v2 __attribute__((ext_vector_type(2)));
static __device__ __forceinline__ v2 sp(float s) { return (v2){s, s}; }
static __device__ __forceinline__ v2 fma2(v2 a, v2 b, v2 c) {
    return __builtin_elementwise_fma(a, b, c);
}
static __device__ __forceinline__ v2 ldv2(const float* p) {
    return *reinterpret_cast<const v2*>(p);
}

// Gabriel pair test, both directions. Op order identical to rounds 2-8.
template <int I, int J>
static __device__ __forceinline__ void gpair(const v2* __restrict__ p,
                                             unsigned& ml, unsigned& mh)
{
    #pragma clang fp contract(off)
    v2 mid = (p[I] + p[J]) * sp(0.5f);
    v2 di = p[I] - mid;  v2 si = di * di;  float r2i = si.x + si.y;
    v2 dj = p[J] - mid;  v2 sj = dj * dj;  float r2j = sj.x + sj.y;
    float dmin = 3.4e38f;
    #pragma unroll
    for (int k = 0; k < 8; ++k) {
        if (k == I || k == J) continue;
        v2 dk = p[k] - mid;
        v2 sk = dk * dk;
        dmin = fminf(dmin, sk.x + sk.y);
    }
    constexpr unsigned bi = 1u << (((I & 3) * 8) + J);  // row I, bit J
    constexpr unsigned bj = 1u << (((J & 3) * 8) + I);  // row J, bit I
    if (I < 4) ml |= (dmin < r2i) ? 0u : bi; else mh |= (dmin < r2i) ? 0u : bi;
    if (J < 4) ml |= (dmin < r2j) ? 0u : bj; else mh |= (dmin < r2j) ? 0u : bj;
}

__global__ __launch_bounds__(256, 8) void gae_main(
    const float* __restrict__ x,        // (B,8)
    const float* __restrict__ enc_w1,   // (3,64)
    const float* __restrict__ enc_b1,   // (64,)
    const float* __restrict__ enc_w2,   // (64,2)
    const float* __restrict__ enc_b2,   // (2,)
    const float* __restrict__ gcn1_w,   // (2,32)
    const float* __restrict__ gcn1_b,   // (32,)
    const float* __restrict__ gcn2_w,   // (32,32)
    const float* __restrict__ gcn2_b,   // (32,)
    const float* __restrict__ dec_w1,   // (32,64)
    const float* __restrict__ dec_b1,   // (64,)
    const float* __restrict__ dec_w2,   // (64,3)
    const float* __restrict__ dec_b2,   // (3,)
    float* __restrict__ out_rec,        // (B,8)
    float* __restrict__ out_lat,        // (B,8,2)
    int B)
{
    __shared__ __align__(16) float smem[4096];            // 16 KB arena
    v2*       const A2 = reinterpret_cast<v2*>(smem);     // [0,2048) as v2[1024]
    unsigned* const MB = reinterpret_cast<unsigned*>(smem + 2048); // [2048,2560)
    v2*       const N2 = reinterpret_cast<v2*>(smem + 2560);       // n rows
    float*    const CJ = smem + 3584;                     // cj rows
    float*    const PL = smem + 2048;                     // pooled [32][64]
    float*    const OO = smem;                            // o [4][64]

    const int lane = threadIdx.x & 63;
    const int ru   = __builtin_amdgcn_readfirstlane(threadIdx.x >> 6); // 0..3
    int g = blockIdx.x * 64 + lane;
    if (g >= B) g = B - 1;

    // ---- load own 2 nodes' x (8B/lane) ----
    const float2 xr = *reinterpret_cast<const float2*>(x + (size_t)g * 8 + 2 * ru);
    const v2 xp2 = (v2){xr.x, xr.y};
    const float i0f = (float)(2 * ru), i1f = i0f + 1.0f;

    // ---- encoder, own 2 nodes (r7 gae_enc form, bit-identical) ----
    v2 pl0, pl1;
    { const v2 b2v = ldv2(enc_b2); pl0 = b2v; pl1 = b2v; }
    #pragma unroll 8
    for (int h = 0; h < 64; ++h) {
        const float wx = enc_w1[64 + h];
        const float wi = enc_w1[128 + h];
        const float bb = enc_b1[h];
        const v2 uxy = ldv2(enc_w2 + 2 * h);
        const float c0 = fmaf(i0f, wi, bb);
        const float c1 = fmaf(i1f, wi, bb);
        v2 t = fma2(xp2, sp(wx), (v2){c0, c1});
        float t0 = fmaxf(t.x, 0.0f);
        float t1 = fmaxf(t.y, 0.0f);
        pl0 = fma2(sp(t0), uxy, pl0);
        pl1 = fma2(sp(t1), uxy, pl1);
    }
    // (global latent store deferred to kernel end)

    // ---- exchange latent: A region = p[8][64] ----
    A2[(2 * ru + 0) * 64 + lane] = pl0;
    A2[(2 * ru + 1) * 64 + lane] = pl1;
    __syncthreads();                                      // barrier 1
    v2 p[8];
    #pragma unroll
    for (int j = 0; j < 8; ++j) p[j] = A2[j * 64 + lane];

    // ---- Gabriel, 7 pairs per role ----
    unsigned ml = 0u, mh = 0u;
    if (ru == 0) {
        gpair<0,1>(p, ml, mh); gpair<0,2>(p, ml, mh); gpair<0,3>(p, ml, mh);
        gpair<0,4>(p, ml, mh); gpair<0,5>(p, ml, mh); gpair<0,6>(p, ml, mh);
        gpair<0,7>(p, ml, mh);
    } else if (ru == 1) {
        gpair<1,2>(p, ml, mh); gpair<1,3>(p, ml, mh); gpair<1,4>(p, ml, mh);
        gpair<1,5>(p, ml, mh); gpair<1,6>(p, ml, mh); gpair<1,7>(p, ml, mh);
        gpair<2,3>(p, ml, mh);
    } else if (ru == 2) {
        gpair<2,4>(p, ml, mh); gpair<2,5>(p, ml, mh); gpair<2,6>(p, ml, mh);
        gpair<2,7>(p, ml, mh); gpair<3,4>(p, ml, mh); gpair<3,5>(p, ml, mh);
        gpair<3,6>(p, ml, mh);
    } else {
        gpair<3,7>(p, ml, mh); gpair<4,5>(p, ml, mh); gpair<4,6>(p, ml, mh);
        gpair<4,7>(p, ml, mh); gpair<5,6>(p, ml, mh); gpair<5,7>(p, ml, mh);
        gpair<6,7>(p, ml, mh);
    }

    // ---- combine masks (+ self loops); layout m[ru][w][lane] ----
    MB[ru * 128 +  0 + lane] = ml;
    MB[ru * 128 + 64 + lane] = mh;
    __syncthreads();                                      // barrier 2
    ml = (MB[0 * 128 + lane] | MB[1 * 128 + lane]) |
         (MB[2 * 128 + lane] | MB[3 * 128 + lane]) | 0x08040201u;
    mh = (MB[0 * 128 + 64 + lane] | MB[1 * 128 + 64 + lane]) |
         (MB[2 * 128 + 64 + lane] | MB[3 * 128 + 64 + lane]) | 0x80402010u;

    // ---- dinv[8], q[8] ----
    float dinv[8];
    v2 q[8];
    #pragma unroll
    for (int i = 0; i < 8; ++i) {
        const unsigned rb = ((i < 4 ? ml : mh) >> ((i & 3) * 8)) & 0xffu;
        dinv[i] = __builtin_amdgcn_rsqf((float)__popc(rb));
        q[i] = sp(dinv[i]) * p[i];
    }

    // ---- own 2 rows of n, own 2 cols of cj; publish to LDS ----
    {
        const unsigned w = (ru < 2) ? ml : mh;
        const int sh = ((2 * ru) & 3) * 8;
        const unsigned rb0 = (w >> sh) & 0xffu;
        const unsigned rb1 = (w >> (sh + 8)) & 0xffu;
        const float dv0 = __builtin_amdgcn_rsqf((float)__popc(rb0));
        const float dv1 = __builtin_amdgcn_rsqf((float)__popc(rb1));
        v2 a0 = sp(0.0f), a1 = sp(0.0f);
        #pragma unroll
        for (int j = 0; j < 8; ++j) {
            a0 = fma2(sp((float)((rb0 >> j) & 1u)), q[j], a0);
            a1 = fma2(sp((float)((rb1 >> j) & 1u)), q[j], a1);
        }
        N2[(2 * ru + 0) * 64 + lane] = sp(dv0) * a0;
        N2[(2 * ru + 1) * 64 + lane] = sp(dv1) * a1;

        const int j0 = 2 * ru, j1 = 2 * ru + 1;
        float s0 = 0.0f, s1 = 0.0f;
        #pragma unroll
        for (int i = 0; i < 8; ++i) {
            const unsigned rb = ((i < 4 ? ml : mh) >> ((i & 3) * 8)) & 0xffu;
            s0 = fmaf((float)((rb >> j0) & 1u), dinv[i], s0);
            s1 = fmaf((float)((rb >> j1) & 1u), dinv[i], s1);
        }
        CJ[j0 * 64 + lane] = 0.125f * dv0 * s0;
        CJ[j1 * 64 + lane] = 0.125f * dv1 * s1;
    }
    __syncthreads();                                      // barrier 3

    // ---- GCN1 + pooled projection, own 8 features ----
    const float* w0 = gcn1_w + 8 * ru;
    const float* w1 = gcn1_w + 32 + 8 * ru;
    const float* bl = gcn1_b + 8 * ru;
    v2 t2[4];
    #pragma unroll
    for (int fp = 0; fp < 4; ++fp) t2[fp] = sp(0.0f);
    #pragma unroll
    for (int i = 0; i < 8; ++i) {
        const v2 ni = N2[i * 64 + lane];
        const float ci = CJ[i * 64 + lane];
        const v2 nxi = sp(ni.x), nyi = sp(ni.y), civ = sp(ci);
        #pragma unroll
        for (int fp = 0; fp < 4; ++fp) {
            v2 h = fma2(nxi, ldv2(w0 + 2 * fp),
                   fma2(nyi, ldv2(w1 + 2 * fp), ldv2(bl + 2 * fp)));
            h = __builtin_elementwise_max(h, sp(0.0f));
            t2[fp] = fma2(civ, h, t2[fp]);
        }
    }

    // ---- exchange t: A region = t[16][64] (p dead since barrier 2) ----
    #pragma unroll
    for (int fp = 0; fp < 4; ++fp) A2[(4 * ru + fp) * 64 + lane] = t2[fp];
    __syncthreads();                                      // barrier 4

    // ---- pooled, own 8 g's (g in [8ru,8ru+8)): r2-proven math ----
    v2 pg2[4];
    #pragma unroll
    for (int kp = 0; kp < 4; ++kp) pg2[kp] = ldv2(gcn2_b + 8 * ru + 2 * kp);
    #pragma unroll
    for (int fp = 0; fp < 16; ++fp) {
        const v2 tv = A2[fp * 64 + lane];                 // ds_read_b64
        #pragma unroll
        for (int half = 0; half < 2; ++half) {
            const int f = 2 * fp + half;
            const v2 tf = sp(half ? tv.y : tv.x);
            const float* wr = gcn2_w + f * 32 + 8 * ru;
            #pragma unroll
            for (int kp = 0; kp < 4; ++kp)
                pg2[kp] = fma2(tf, ldv2(wr + 2 * kp), pg2[kp]);
        }
    }
    // publish pooled rows (overwrites masks + n/cj regions, both dead)
    #pragma unroll
    for (int kp = 0; kp < 4; ++kp) {
        PL[(8 * ru + 2 * kp + 0) * 64 + lane] = pg2[kp].x;
        PL[(8 * ru + 2 * kp + 1) * 64 + lane] = pg2[kp].y;
    }
    __syncthreads();                                      // barrier 5

    // ---- decoder, own 16 h's (h in [16ru,16ru+16)): r2-proven math ----
    const float* db = dec_b1 + 16 * ru;
    v2 a2[8];
    #pragma unroll
    for (int hp = 0; hp < 8; ++hp) a2[hp] = ldv2(db + 2 * hp);
    __builtin_amdgcn_s_setprio(1);
    #pragma unroll
    for (int f = 0; f < 32; ++f) {
        const float pf = PL[f * 64 + lane];               // ds_read_b32
        const v2 pfv = sp(pf);
        const float* wr = dec_w1 + f * 64 + 16 * ru;
        #pragma unroll
        for (int hp = 0; hp < 8; ++hp)
            a2[hp] = fma2(pfv, ldv2(wr + 2 * hp), a2[hp]);
    }
    __builtin_amdgcn_s_setprio(0);
    v2 oacc = sp(0.0f);
    #pragma unroll
    for (int hp = 0; hp < 8; ++hp) {
        v2 rr = __builtin_elementwise_max(a2[hp], sp(0.0f));
        const int h0 = 16 * ru + 2 * hp;
        const v2 wv = (v2){dec_w2[h0 * 3 + 1], dec_w2[h0 * 3 + 4]};
        oacc = fma2(rr, wv, oacc);
    }
    const float opart = oacc.x + oacc.y;

    // ---- combine 4 partials (same tree as r4-r8) ----
    OO[ru * 64 + lane] = opart;          // A region rows 0-1 (t dead pre-bar5)
    __syncthreads();                                      // barrier 6
    const float outv = ((OO[lane] + OO[64 + lane]) +
                        (OO[128 + lane] + OO[192 + lane])) + dec_b2[1];

    // ---- all global stores at the end ----
    *reinterpret_cast<float4*>(out_lat + (size_t)g * 16 + 4 * ru) =
        make_float4(pl0.x, pl0.y, pl1.x, pl1.y);
    *reinterpret_cast<float2*>(out_rec + (size_t)g * 8 + 2 * ru) =
        make_float2(outv, outv);
}

extern "C" void kernel_launch(void* const* d_in, const int* in_sizes, int n_in,
                              void* d_out, int out_size, void* d_ws, size_t ws_size,
                              hipStream_t stream) {
    const float* x       = (const float*)d_in[0];
    const float* enc_w1  = (const float*)d_in[1];
    const float* enc_b1  = (const float*)d_in[2];
    const float* enc_w2  = (const float*)d_in[3];
    const float* enc_b2  = (const float*)d_in[4];
    const float* gcn1_w  = (const float*)d_in[5];
    const float* gcn1_b  = (const float*)d_in[6];
    const float* gcn2_w  = (const float*)d_in[7];
    const float* gcn2_b  = (const float*)d_in[8];
    const float* dec_w1  = (const float*)d_in[9];
    const float* dec_b1  = (const float*)d_in[10];
    const float* dec_w2  = (const float*)d_in[11];
    const float* dec_b2  = (const float*)d_in[12];

    const int B = in_sizes[0] / 8;
    float* out_rec = (float*)d_out;                 // (B,8)
    float* out_lat = out_rec + (size_t)B * 8;       // (B,8,2)
    (void)d_ws; (void)ws_size;                      // workspace unused

    const int blocks = (B + 63) / 64;               // 64 graphs per block
    gae_main<<<blocks, 256, 0, stream>>>(
        x, enc_w1, enc_b1, enc_w2, enc_b2,
        gcn1_w, gcn1_b, gcn2_w, gcn2_b,
        dec_w1, dec_b1, dec_w2, dec_b2,
        out_rec, out_lat, B);
}